// Round 8
// baseline (272.159 us; speedup 1.0000x reference)
//
#include <hip/hip_runtime.h>

#define EDGES 800000
#define NODES 50000
#define CH 28        // NS + 3*NV
#define NWT 400      // n_weights
#define SCAN_NB 196  // ceil(NODES/256)
#define FIXS 65536.0f      // fixed-point scale 2^16
#define FIXR (1.0f/65536.0f)

typedef __attribute__((ext_vector_type(8))) short bf16x8;
typedef __attribute__((ext_vector_type(4))) float f32x4;

// Compiler-only ordering fence: prevents LLVM from reordering LDS ops across
// same-wave cross-lane handoffs (per-lane alias analysis + TBAA would
// otherwise allow hoisting writes above reads -> cross-lane corruption,
// the R4-R7 failure class).
#define WAVE_FENCE() __builtin_amdgcn_sched_barrier(0)

// software round-to-nearest-even f32->bf16 (v_cvt_pk_bf16_f32 is NOT RNE-safe
// for GEMM operands: R4 showed absmax growth from biased rounding)
__device__ __forceinline__ short f2bf(float f) {
    union { float f; unsigned u; } v; v.f = f;
    unsigned r = v.u + 0x7FFFu + ((v.u >> 16) & 1u);   // RNE
    return (short)(r >> 16);
}

// XOR swizzle for 128B-row LDS tiles (breaks 16-way conflict on b128 column reads)
#define SWZ(b, row) ((b) ^ (((row) & 7) << 4))

// ============================================================================
// Sort prep (R3-exact): histogram -> exclusive scan -> scan3 -> placement
// ============================================================================
__global__ __launch_bounds__(256) void hist_kernel(const int* __restrict__ eidx,
                                                   int* __restrict__ counts) {
    int e = blockIdx.x * 256 + threadIdx.x;
    if (e < EDGES) atomicAdd(&counts[eidx[e]], 1);
}

__global__ __launch_bounds__(256) void scan1_kernel(const int* __restrict__ counts,
                                                    int* __restrict__ offsets,
                                                    int* __restrict__ bsum) {
    __shared__ int tmp[256];
    int t = threadIdx.x;
    int i = blockIdx.x * 256 + t;
    int v = (i < NODES) ? counts[i] : 0;
    tmp[t] = v;
    __syncthreads();
    int x = v;
    for (int d = 1; d < 256; d <<= 1) {
        int y = (t >= d) ? tmp[t - d] : 0;
        __syncthreads();
        x += y; tmp[t] = x;
        __syncthreads();
    }
    if (i < NODES) offsets[i] = x - v;
    if (t == 255) bsum[blockIdx.x] = x;
}

__global__ __launch_bounds__(256) void scan2_kernel(int* __restrict__ bsum) {
    __shared__ int tmp[256];
    int t = threadIdx.x;
    int v = (t < SCAN_NB) ? bsum[t] : 0;
    tmp[t] = v;
    __syncthreads();
    int x = v;
    for (int d = 1; d < 256; d <<= 1) {
        int y = (t >= d) ? tmp[t - d] : 0;
        __syncthreads();
        x += y; tmp[t] = x;
        __syncthreads();
    }
    if (t < SCAN_NB) bsum[t] = x - v;
}

__global__ __launch_bounds__(256) void scan3_kernel(int* __restrict__ offsets,
                                                    const int* __restrict__ bsum) {
    int i = blockIdx.x * 256 + threadIdx.x;
    if (i < NODES) offsets[i] += bsum[blockIdx.x];
}

__global__ __launch_bounds__(256) void perm_kernel(const int* __restrict__ eidx,
                                                   const int* __restrict__ offsets,
                                                   int* __restrict__ cursor,
                                                   int* __restrict__ perm) {
    int e = blockIdx.x * 256 + threadIdx.x;
    if (e < EDGES) {
        int s = eidx[e];
        int pos = offsets[s] + atomicAdd(&cursor[s], 1);
        perm[pos] = e;
    }
}

// ============================================================================
// Main (R3 body + wave fences + int32 fixed-point scatter)
// ============================================================================
__global__ __launch_bounds__(256, 2) void tpconv_kernel(
    const float* __restrict__ node_attr,
    const float* __restrict__ edge_attr,
    const float* __restrict__ edge_sh,
    const int*   __restrict__ eidx,
    const float* __restrict__ W1,
    const float* __restrict__ b1,
    const float* __restrict__ W2,
    const float* __restrict__ b2,
    int* __restrict__ outq,            // [N][28] int32 fixed-point accumulator (= d_out)
    const int* __restrict__ perm)
{
    __shared__ __align__(16) short w2t[NWT * 64];    // W2^T bf16, swizzled
    __shared__ float b2s[NWT];
    __shared__ __align__(16) short hbuf[4][16 * 64]; // per-wave h tile; reused as stf[16][28] f32
    __shared__ float edata[4][16 * 53];              // per-wave per-edge coefficients
    __shared__ int   srcb[4][16];
    __shared__ int   eids[4][16];

    const int tid  = threadIdx.x;
    const int lane = tid & 63;
    const int wid  = tid >> 6;
    const int cl   = lane & 15;   // col within fragment / edge-in-tile
    const int qd   = lane >> 4;   // lane quad

    // ---- stage W2^T (bf16, swizzled) + b2 : once per block (R3-exact) ----
    for (int f = tid; f < NWT * 64; f += 256) {
        int n = f >> 6, j = f & 63;
        int byte = SWZ(n * 128 + j * 2, n);
        w2t[byte >> 1] = f2bf(W2[j * NWT + n]);
    }
    for (int f = tid; f < NWT; f += 256) b2s[f] = b2[f];

    // ---- per-lane W1 fragments (B of GEMM1) + b1 ----
    float b1v[4];
    bf16x8 w1f[2][4];
    #pragma unroll
    for (int nt = 0; nt < 4; ++nt) {
        b1v[nt] = b1[nt * 16 + cl];
        #pragma unroll
        for (int ks = 0; ks < 2; ++ks) {
            bf16x8 fr;
            #pragma unroll
            for (int i = 0; i < 8; ++i) {
                int k = ks * 32 + qd * 8 + i;
                fr[i] = f2bf(W1[k * 64 + nt * 16 + cl]);
            }
            w1f[ks][nt] = fr;
        }
    }
    __syncthreads();

    const float INV3 = 0.57735026919f;      // 1/sqrt(3)
    const float CS_  = 0.17677669529f;      // (1/sqrt(16)) * (1/sqrt(2))
    const float CV_  = 0.35355339059f;      // (1/sqrt(4))  * (1/sqrt(2))

    const int tiles = EDGES / 16;           // 50000, exact
    for (int tile = blockIdx.x * 4 + wid; tile < tiles; tile += gridDim.x * 4) {
        const int ebase = tile * 16;

        // ---- per-edge coefficient precompute (lanes 0..15, one edge each) ----
        if (lane < 16) {
            const int slot = ebase + lane;
            const int e  = perm[slot];
            const int s  = eidx[e];
            const int dn = eidx[EDGES + e];
            srcb[wid][lane] = s;
            eids[wid][lane] = e;
            const float4 sh4 = *reinterpret_cast<const float4*>(edge_sh + (size_t)e * 4);
            float xs[16], xv[12];
            {
                const float4* xp = reinterpret_cast<const float4*>(node_attr + (size_t)dn * CH);
                float4 q0 = xp[0], q1 = xp[1], q2 = xp[2], q3 = xp[3], q4 = xp[4], q5 = xp[5], q6 = xp[6];
                xs[0]=q0.x; xs[1]=q0.y; xs[2]=q0.z; xs[3]=q0.w;
                xs[4]=q1.x; xs[5]=q1.y; xs[6]=q1.z; xs[7]=q1.w;
                xs[8]=q2.x; xs[9]=q2.y; xs[10]=q2.z; xs[11]=q2.w;
                xs[12]=q3.x; xs[13]=q3.y; xs[14]=q3.z; xs[15]=q3.w;
                xv[0]=q4.x; xv[1]=q4.y; xv[2]=q4.z; xv[3]=q4.w;
                xv[4]=q5.x; xv[5]=q5.y; xv[6]=q5.z; xv[7]=q5.w;
                xv[8]=q6.x; xv[9]=q6.y; xv[10]=q6.z; xv[11]=q6.w;
            }
            const float shs = sh4.x, sv0 = sh4.y, sv1 = sh4.z, sv2 = sh4.w;
            float* ed = &edata[wid][lane * 53];
            #pragma unroll
            for (int i = 0; i < 16; ++i) {
                ed[i]      = xs[i] * shs * CS_;   // a_s
                ed[20 + i] = xs[i] * CS_;         // b_s
            }
            #pragma unroll
            for (int v = 0; v < 4; ++v) {
                float dot = (xv[3*v] * sv0 + xv[3*v+1] * sv1 + xv[3*v+2] * sv2) * INV3;
                ed[16 + v] = dot * CV_;           // a_v
                ed[36 + 3*v + 0] = xv[3*v + 0] * shs * CV_;   // xvs
                ed[36 + 3*v + 1] = xv[3*v + 1] * shs * CV_;
                ed[36 + 3*v + 2] = xv[3*v + 2] * shs * CV_;
            }
            ed[48] = sv0; ed[49] = sv1; ed[50] = sv2;
        }
        WAVE_FENCE();   // edata/srcb/eids written by lanes<16, read by all lanes below

        // ---- GEMM1 A fragments from global (row gather), f32 -> bf16 ----
        const int es = eids[wid][cl];
        const float4* ap = reinterpret_cast<const float4*>(edge_attr + (size_t)es * 64);
        float4 a0 = ap[qd*2], a1 = ap[qd*2 + 1], a2 = ap[8 + qd*2], a3 = ap[8 + qd*2 + 1];
        bf16x8 af0, af1;
        af0[0]=f2bf(a0.x); af0[1]=f2bf(a0.y); af0[2]=f2bf(a0.z); af0[3]=f2bf(a0.w);
        af0[4]=f2bf(a1.x); af0[5]=f2bf(a1.y); af0[6]=f2bf(a1.z); af0[7]=f2bf(a1.w);
        af1[0]=f2bf(a2.x); af1[1]=f2bf(a2.y); af1[2]=f2bf(a2.z); af1[3]=f2bf(a2.w);
        af1[4]=f2bf(a3.x); af1[5]=f2bf(a3.y); af1[6]=f2bf(a3.z); af1[7]=f2bf(a3.w);

        // ---- GEMM1: h = relu(A @ W1 + b1), write bf16 h tile to LDS ----
        short* hb = hbuf[wid];
        #pragma unroll
        for (int nt = 0; nt < 4; ++nt) {
            f32x4 acc = { b1v[nt], b1v[nt], b1v[nt], b1v[nt] };
            acc = __builtin_amdgcn_mfma_f32_16x16x32_bf16(af0, w1f[0][nt], acc, 0, 0, 0);
            acc = __builtin_amdgcn_mfma_f32_16x16x32_bf16(af1, w1f[1][nt], acc, 0, 0, 0);
            #pragma unroll
            for (int r = 0; r < 4; ++r) {
                int m = qd * 4 + r;
                float hv = fmaxf(acc[r], 0.0f);
                int byte = SWZ(m * 128 + (nt * 16 + cl) * 2, m);
                hb[byte >> 1] = f2bf(hv);
            }
        }
        WAVE_FENCE();   // h tile written by all lanes, fragments read cross-lane

        // ---- h fragments back (A of GEMM2) ----
        bf16x8 h0 = *reinterpret_cast<bf16x8*>(reinterpret_cast<char*>(hb) + SWZ(cl * 128 + qd * 16, cl));
        bf16x8 h1 = *reinterpret_cast<bf16x8*>(reinterpret_cast<char*>(hb) + SWZ(cl * 128 + 64 + qd * 16, cl));
        WAVE_FENCE();   // stf writes below reuse hb: must not hoist above these reads

        // ---- GEMM2 over 25 column tiles, fused tensor-product consume ----
        f32x4 outs = {0.f, 0.f, 0.f, 0.f};
        f32x4 pacc = {0.f, 0.f, 0.f, 0.f};
        float qacc[4][3] = {{0,0,0},{0,0,0},{0,0,0},{0,0,0}};
        const float* edw = edata[wid];
        const char* wb = reinterpret_cast<const char*>(w2t);
        #pragma unroll
        for (int ct = 0; ct < 25; ++ct) {
            int n = ct * 16 + cl;
            bf16x8 bf0 = *reinterpret_cast<const bf16x8*>(wb + SWZ(n * 128 + qd * 16, n));
            bf16x8 bf1 = *reinterpret_cast<const bf16x8*>(wb + SWZ(n * 128 + 64 + qd * 16, n));
            float bb = b2s[n];
            f32x4 t = { bb, bb, bb, bb };
            t = __builtin_amdgcn_mfma_f32_16x16x32_bf16(h0, bf0, t, 0, 0, 0);
            t = __builtin_amdgcn_mfma_f32_16x16x32_bf16(h1, bf1, t, 0, 0, 0);
            if (ct < 16) {
                #pragma unroll
                for (int r = 0; r < 4; ++r)
                    outs[r] += edw[(qd*4 + r) * 53 + ct] * t[r];
            } else if (ct < 20) {
                #pragma unroll
                for (int r = 0; r < 4; ++r)
                    outs[r] += edw[(qd*4 + r) * 53 + 16 + (ct - 16)] * t[r];
            } else if (ct < 24) {
                int il = cl >> 2;
                #pragma unroll
                for (int r = 0; r < 4; ++r)
                    pacc[r] += edw[(qd*4 + r) * 53 + 20 + 4*(ct - 20) + il] * t[r];
            } else {
                int v = cl >> 2;
                #pragma unroll
                for (int r = 0; r < 4; ++r) {
                    #pragma unroll
                    for (int d = 0; d < 3; ++d)
                        qacc[r][d] += edw[(qd*4 + r) * 53 + 36 + 3*v + d] * t[r];
                }
            }
        }

        // ---- butterfly-reduce P,Q over the 4 sub-columns ----
        #pragma unroll
        for (int r = 0; r < 4; ++r) {
            float p = pacc[r];
            p += __shfl_xor(p, 4);
            p += __shfl_xor(p, 8);
            pacc[r] = p;
            #pragma unroll
            for (int d = 0; d < 3; ++d) {
                float q = qacc[r][d];
                q += __shfl_xor(q, 4);
                q += __shfl_xor(q, 8);
                qacc[r][d] = q;
            }
        }

        // ---- assemble 16x28 tile in LDS (reuse hbuf region, R3-exact) ----
        float* stf = reinterpret_cast<float*>(hb);
        #pragma unroll
        for (int r = 0; r < 4; ++r)
            stf[(qd*4 + r) * CH + cl] = outs[r];
        if (cl < 12) {
            int o = cl & 3, d = cl >> 2;
            #pragma unroll
            for (int r = 0; r < 4; ++r) {
                int m = qd * 4 + r;
                float qv = (d == 0) ? qacc[r][0] : ((d == 1) ? qacc[r][1] : qacc[r][2]);
                stf[m * CH + 16 + o * 3 + d] = edw[m * 53 + 48 + d] * pacc[r] + qv;
            }
        }
        WAVE_FENCE();   // stf written by all lanes, scatter reads cross-lane

        // ---- segmented scatter: runs of equal src -> int32 fixed-point atomics ----
        if (lane < CH) {
            int cur = srcb[wid][0];
            float acc2 = 0.0f;
            for (int m = 0; m < 16; ++m) {
                int s = srcb[wid][m];
                if (s != cur) {
                    atomicAdd(&outq[(size_t)cur * CH + lane], (int)rintf(acc2 * FIXS));
                    acc2 = 0.0f; cur = s;
                }
                acc2 += stf[m * CH + lane];
            }
            atomicAdd(&outq[(size_t)cur * CH + lane], (int)rintf(acc2 * FIXS));
        }
        WAVE_FENCE();   // next iteration's edata/h writes must not overlap scatter reads
    }
}

// finalize: all accesses to d_out through int* (no int/float TBAA hazard)
__global__ __launch_bounds__(256) void finalize_kernel(int* __restrict__ outq,
                                                       const int* __restrict__ counts,
                                                       const float* __restrict__ node_attr) {
    int idx = blockIdx.x * 256 + threadIdx.x;
    if (idx < NODES * CH) {
        int n = idx / CH;
        int q = outq[idx];
        float r = ((float)q * FIXR) / fmaxf((float)counts[n], 1.0f) + node_attr[idx];
        outq[idx] = __float_as_int(r);
    }
}

extern "C" void kernel_launch(void* const* d_in, const int* in_sizes, int n_in,
                              void* d_out, int out_size, void* d_ws, size_t ws_size,
                              hipStream_t stream) {
    const float* node_attr = (const float*)d_in[0];
    const float* edge_attr = (const float*)d_in[1];
    const float* edge_sh   = (const float*)d_in[2];
    const int*   eidx      = (const int*)d_in[3];
    const float* W1 = (const float*)d_in[4];
    const float* b1 = (const float*)d_in[5];
    const float* W2 = (const float*)d_in[6];
    const float* b2 = (const float*)d_in[7];

    // ws layout (bytes): counts@0, offsets@204800, cursor@409600, bsum@614400, perm@616448
    const size_t OFF_OFFSETS = 204800;
    const size_t OFF_CURSOR  = 409600;
    const size_t OFF_BSUM    = 614400;
    const size_t OFF_PERM    = 616448;

    int* counts  = (int*)d_ws;
    int* offsets = (int*)((char*)d_ws + OFF_OFFSETS);
    int* cursor  = (int*)((char*)d_ws + OFF_CURSOR);
    int* bsum    = (int*)((char*)d_ws + OFF_BSUM);
    int* perm    = (int*)((char*)d_ws + OFF_PERM);

    const int EB = (EDGES + 255) / 256;  // 3125

    hipMemsetAsync(counts, 0, NODES * sizeof(int), stream);
    hipMemsetAsync(cursor, 0, NODES * sizeof(int), stream);
    hipMemsetAsync(d_out, 0, (size_t)NODES * CH * sizeof(float), stream);

    hist_kernel<<<EB, 256, 0, stream>>>(eidx, counts);
    scan1_kernel<<<SCAN_NB, 256, 0, stream>>>(counts, offsets, bsum);
    scan2_kernel<<<1, 256, 0, stream>>>(bsum);
    scan3_kernel<<<SCAN_NB, 256, 0, stream>>>(offsets, bsum);
    perm_kernel<<<EB, 256, 0, stream>>>(eidx, offsets, cursor, perm);

    tpconv_kernel<<<512, 256, 0, stream>>>(node_attr, edge_attr, edge_sh, eidx,
                                           W1, b1, W2, b2, (int*)d_out, perm);
    finalize_kernel<<<(NODES * CH + 255) / 256, 256, 0, stream>>>((int*)d_out, counts, node_attr);
}

// Round 9
// 270.195 us; speedup vs baseline: 1.0073x; 1.0073x over previous
//
#include <hip/hip_runtime.h>

#define EDGES 800000
#define NODES 50000
#define CH 28        // NS + 3*NV
#define NWT 400      // n_weights
#define SCAN_NB 196  // ceil(NODES/256)
#define FIXS 65536.0f      // fixed-point scale 2^16
#define FIXR (1.0f/65536.0f)

typedef __attribute__((ext_vector_type(8))) short bf16x8;
typedef __attribute__((ext_vector_type(4))) float f32x4;

// Compiler-only ordering fence: prevents LLVM from reordering LDS ops across
// same-wave cross-lane handoffs (per-lane alias analysis + TBAA would
// otherwise allow hoisting writes above reads -> cross-lane corruption,
// the R4-R7 failure class).
#define WAVE_FENCE() __builtin_amdgcn_sched_barrier(0)

// software round-to-nearest-even f32->bf16 (v_cvt_pk_bf16_f32 is NOT RNE-safe
// for GEMM operands: R4 showed absmax growth from biased rounding)
__device__ __forceinline__ short f2bf(float f) {
    union { float f; unsigned u; } v; v.f = f;
    unsigned r = v.u + 0x7FFFu + ((v.u >> 16) & 1u);   // RNE
    return (short)(r >> 16);
}

__device__ __forceinline__ bf16x8 pack8(float4 u, float4 v) {
    bf16x8 h;
    h[0] = f2bf(u.x); h[1] = f2bf(u.y); h[2] = f2bf(u.z); h[3] = f2bf(u.w);
    h[4] = f2bf(v.x); h[5] = f2bf(v.y); h[6] = f2bf(v.z); h[7] = f2bf(v.w);
    return h;
}

// XOR swizzle for 128B-row LDS tiles (breaks 16-way conflict on b128 column reads)
#define SWZ(b, row) ((b) ^ (((row) & 7) << 4))

// ============================================================================
// Sort prep (R3/R8-exact)
// ============================================================================
__global__ __launch_bounds__(256) void hist_kernel(const int* __restrict__ eidx,
                                                   int* __restrict__ counts) {
    int e = blockIdx.x * 256 + threadIdx.x;
    if (e < EDGES) atomicAdd(&counts[eidx[e]], 1);
}

__global__ __launch_bounds__(256) void scan1_kernel(const int* __restrict__ counts,
                                                    int* __restrict__ offsets,
                                                    int* __restrict__ bsum) {
    __shared__ int tmp[256];
    int t = threadIdx.x;
    int i = blockIdx.x * 256 + t;
    int v = (i < NODES) ? counts[i] : 0;
    tmp[t] = v;
    __syncthreads();
    int x = v;
    for (int d = 1; d < 256; d <<= 1) {
        int y = (t >= d) ? tmp[t - d] : 0;
        __syncthreads();
        x += y; tmp[t] = x;
        __syncthreads();
    }
    if (i < NODES) offsets[i] = x - v;
    if (t == 255) bsum[blockIdx.x] = x;
}

__global__ __launch_bounds__(256) void scan2_kernel(int* __restrict__ bsum) {
    __shared__ int tmp[256];
    int t = threadIdx.x;
    int v = (t < SCAN_NB) ? bsum[t] : 0;
    tmp[t] = v;
    __syncthreads();
    int x = v;
    for (int d = 1; d < 256; d <<= 1) {
        int y = (t >= d) ? tmp[t - d] : 0;
        __syncthreads();
        x += y; tmp[t] = x;
        __syncthreads();
    }
    if (t < SCAN_NB) bsum[t] = x - v;
}

__global__ __launch_bounds__(256) void scan3_kernel(int* __restrict__ offsets,
                                                    const int* __restrict__ bsum) {
    int i = blockIdx.x * 256 + threadIdx.x;
    if (i < NODES) offsets[i] += bsum[blockIdx.x];
}

__global__ __launch_bounds__(256) void perm_kernel(const int* __restrict__ eidx,
                                                   const int* __restrict__ offsets,
                                                   int* __restrict__ cursor,
                                                   int* __restrict__ perm) {
    int e = blockIdx.x * 256 + threadIdx.x;
    if (e < EDGES) {
        int s = eidx[e];
        int pos = offsets[s] + atomicAdd(&cursor[s], 1);
        perm[pos] = e;
    }
}

// ============================================================================
// Main: R8 body + 2-deep register pipeline for the gather chain.
// All four R4-R7 bug classes stay fixed: f2bf RNE, WAVE_FENCE at every LDS
// handoff, int32 fixed-point atomics, int-only finalize.
// ============================================================================
struct TileRegs {
    float4 a0, a1, a2, a3;   // edge_attr quads (per-lane k slices of own edge)
    float4 sh;               // edge_sh row of own edge
    float4 x0, x1, x2, x3;   // node_attr quads (lanes<16: xs; lanes16-31: xv in x0..x2)
    int es, src;
};

__global__ __launch_bounds__(256, 2) void tpconv_kernel(
    const float* __restrict__ node_attr,
    const float* __restrict__ edge_attr,
    const float* __restrict__ edge_sh,
    const int*   __restrict__ eidx,
    const float* __restrict__ W1,
    const float* __restrict__ b1,
    const float* __restrict__ W2,
    const float* __restrict__ b2,
    int* __restrict__ outq,            // [N][28] int32 fixed-point accumulator (= d_out)
    const int* __restrict__ perm)
{
    __shared__ __align__(16) short w2t[NWT * 64];    // W2^T bf16, swizzled
    __shared__ float b2s[NWT];
    __shared__ __align__(16) short hbuf[4][16 * 64]; // per-wave h tile; reused as stf[16][28] f32
    __shared__ float edata[4][16 * 53];              // per-wave per-edge coefficients
    __shared__ int   srcb[4][16];

    const int tid  = threadIdx.x;
    const int lane = tid & 63;
    const int wid  = tid >> 6;
    const int cl   = lane & 15;   // col within fragment / edge-in-tile
    const int qd   = lane >> 4;   // lane quad

    // ---- stage W2^T (bf16, swizzled) + b2 : once per block ----
    for (int f = tid; f < NWT * 64; f += 256) {
        int n = f >> 6, j = f & 63;
        int byte = SWZ(n * 128 + j * 2, n);
        w2t[byte >> 1] = f2bf(W2[j * NWT + n]);
    }
    for (int f = tid; f < NWT; f += 256) b2s[f] = b2[f];

    // ---- per-lane W1 fragments (B of GEMM1) + b1 ----
    float b1v[4];
    bf16x8 w1f[2][4];
    #pragma unroll
    for (int nt = 0; nt < 4; ++nt) {
        b1v[nt] = b1[nt * 16 + cl];
        #pragma unroll
        for (int ks = 0; ks < 2; ++ks) {
            bf16x8 fr;
            #pragma unroll
            for (int i = 0; i < 8; ++i) {
                int k = ks * 32 + qd * 8 + i;
                fr[i] = f2bf(W1[k * 64 + nt * 16 + cl]);
            }
            w1f[ks][nt] = fr;
        }
    }
    __syncthreads();

    const float INV3 = 0.57735026919f;      // 1/sqrt(3)
    const float CS_  = 0.17677669529f;      // (1/sqrt(16)) * (1/sqrt(2))
    const float CV_  = 0.35355339059f;      // (1/sqrt(4))  * (1/sqrt(2))

    const int tiles  = EDGES / 16;          // 50000, exact
    const int STRIDE = gridDim.x << 2;
    const int w0     = blockIdx.x * 4 + wid;

    short* hb  = hbuf[wid];
    float* edwv = edata[wid];
    const char* wb = reinterpret_cast<const char*>(w2t);

    // ---------------- pipelined prologue: load C fully, prefetch N.es ----------------
    TileRegs C, N;
    {
        int slot = w0 * 16 + cl;
        C.es  = perm[slot];
        C.src = eidx[C.es];
        int dst = eidx[EDGES + C.es];
        const float4* ap = reinterpret_cast<const float4*>(edge_attr + (size_t)C.es * 64);
        C.a0 = ap[qd*2]; C.a1 = ap[qd*2+1]; C.a2 = ap[8+qd*2]; C.a3 = ap[8+qd*2+1];
        C.sh = *reinterpret_cast<const float4*>(edge_sh + (size_t)C.es * 4);
        if (lane < 32) {
            const float4* xp = reinterpret_cast<const float4*>(node_attr + (size_t)dst * CH);
            if (lane < 16) { C.x0 = xp[0]; C.x1 = xp[1]; C.x2 = xp[2]; C.x3 = xp[3]; }
            else           { C.x0 = xp[4]; C.x1 = xp[5]; C.x2 = xp[6]; }
        }
        int t1 = w0 + STRIDE;
        int slot1 = (t1 < tiles) ? t1 * 16 + cl : cl;
        N.es = perm[slot1];
    }

    for (int t = w0; t < tiles; t += STRIDE) {
        // ---- top: prefetch perm(t+2S); issue N.es-indexed loads for t+S ----
        int t2 = t + 2 * STRIDE;
        int slot2 = (t2 < tiles) ? t2 * 16 + cl : cl;
        int esF = perm[slot2];

        N.src = eidx[N.es];
        int ndst = eidx[EDGES + N.es];
        {
            const float4* ap = reinterpret_cast<const float4*>(edge_attr + (size_t)N.es * 64);
            N.a0 = ap[qd*2]; N.a1 = ap[qd*2+1]; N.a2 = ap[8+qd*2]; N.a3 = ap[8+qd*2+1];
            N.sh = *reinterpret_cast<const float4*>(edge_sh + (size_t)N.es * 4);
        }

        // ---- edata phase from C (lanes 0..31), R8-exact math ----
        {
            const float shs = C.sh.x, sv0 = C.sh.y, sv1 = C.sh.z, sv2 = C.sh.w;
            float* ed = &edwv[cl * 53];
            if (lane < 16) {
                srcb[wid][cl] = C.src;
                float xs[16] = { C.x0.x, C.x0.y, C.x0.z, C.x0.w,
                                 C.x1.x, C.x1.y, C.x1.z, C.x1.w,
                                 C.x2.x, C.x2.y, C.x2.z, C.x2.w,
                                 C.x3.x, C.x3.y, C.x3.z, C.x3.w };
                #pragma unroll
                for (int i = 0; i < 16; ++i) {
                    ed[i]      = xs[i] * shs * CS_;   // a_s
                    ed[20 + i] = xs[i] * CS_;         // b_s
                }
            } else if (lane < 32) {
                float xv[12] = { C.x0.x, C.x0.y, C.x0.z, C.x0.w,
                                 C.x1.x, C.x1.y, C.x1.z, C.x1.w,
                                 C.x2.x, C.x2.y, C.x2.z, C.x2.w };
                #pragma unroll
                for (int v = 0; v < 4; ++v) {
                    float dot = (xv[3*v] * sv0 + xv[3*v+1] * sv1 + xv[3*v+2] * sv2) * INV3;
                    ed[16 + v] = dot * CV_;                       // a_v
                    ed[36 + 3*v + 0] = xv[3*v + 0] * shs * CV_;   // xvs
                    ed[36 + 3*v + 1] = xv[3*v + 1] * shs * CV_;
                    ed[36 + 3*v + 2] = xv[3*v + 2] * shs * CV_;
                }
                ed[48] = sv0; ed[49] = sv1; ed[50] = sv2;
            }
        }
        WAVE_FENCE();   // edata/srcb written by lanes<32, read by all lanes below

        // ---- GEMM1: h = relu(A @ W1 + b1) from C regs -> bf16 h tile in LDS ----
        {
            bf16x8 af0 = pack8(C.a0, C.a1);
            bf16x8 af1 = pack8(C.a2, C.a3);
            #pragma unroll
            for (int nt = 0; nt < 4; ++nt) {
                f32x4 acc = { b1v[nt], b1v[nt], b1v[nt], b1v[nt] };
                acc = __builtin_amdgcn_mfma_f32_16x16x32_bf16(af0, w1f[0][nt], acc, 0, 0, 0);
                acc = __builtin_amdgcn_mfma_f32_16x16x32_bf16(af1, w1f[1][nt], acc, 0, 0, 0);
                #pragma unroll
                for (int r = 0; r < 4; ++r) {
                    int m = qd * 4 + r;
                    float hv = fmaxf(acc[r], 0.0f);
                    int byte = SWZ(m * 128 + (nt * 16 + cl) * 2, m);
                    hb[byte >> 1] = f2bf(hv);
                }
            }
        }
        WAVE_FENCE();   // h tile written by all lanes, fragments read cross-lane

        // ---- mid: issue node_attr loads for t+S (ndst has returned by now) ----
        if (lane < 32) {
            const float4* xp = reinterpret_cast<const float4*>(node_attr + (size_t)ndst * CH);
            if (lane < 16) { N.x0 = xp[0]; N.x1 = xp[1]; N.x2 = xp[2]; N.x3 = xp[3]; }
            else           { N.x0 = xp[4]; N.x1 = xp[5]; N.x2 = xp[6]; }
        }

        // ---- h fragments back (A of GEMM2) ----
        bf16x8 h0 = *reinterpret_cast<bf16x8*>(reinterpret_cast<char*>(hb) + SWZ(cl * 128 + qd * 16, cl));
        bf16x8 h1 = *reinterpret_cast<bf16x8*>(reinterpret_cast<char*>(hb) + SWZ(cl * 128 + 64 + qd * 16, cl));
        WAVE_FENCE();   // stf writes below reuse hb: must not hoist above these reads

        // ---- GEMM2 over 25 column tiles, fused tensor-product consume ----
        f32x4 outs = {0.f, 0.f, 0.f, 0.f};
        f32x4 pacc = {0.f, 0.f, 0.f, 0.f};
        float qacc[4][3] = {{0,0,0},{0,0,0},{0,0,0},{0,0,0}};
        const float* edw = edwv;
        #pragma unroll
        for (int ct = 0; ct < 25; ++ct) {
            int n = ct * 16 + cl;
            bf16x8 bf0 = *reinterpret_cast<const bf16x8*>(wb + SWZ(n * 128 + qd * 16, n));
            bf16x8 bf1 = *reinterpret_cast<const bf16x8*>(wb + SWZ(n * 128 + 64 + qd * 16, n));
            float bb = b2s[n];
            f32x4 tt = { bb, bb, bb, bb };
            tt = __builtin_amdgcn_mfma_f32_16x16x32_bf16(h0, bf0, tt, 0, 0, 0);
            tt = __builtin_amdgcn_mfma_f32_16x16x32_bf16(h1, bf1, tt, 0, 0, 0);
            if (ct < 16) {
                #pragma unroll
                for (int r = 0; r < 4; ++r)
                    outs[r] += edw[(qd*4 + r) * 53 + ct] * tt[r];
            } else if (ct < 20) {
                #pragma unroll
                for (int r = 0; r < 4; ++r)
                    outs[r] += edw[(qd*4 + r) * 53 + 16 + (ct - 16)] * tt[r];
            } else if (ct < 24) {
                int il = cl >> 2;
                #pragma unroll
                for (int r = 0; r < 4; ++r)
                    pacc[r] += edw[(qd*4 + r) * 53 + 20 + 4*(ct - 20) + il] * tt[r];
            } else {
                int v = cl >> 2;
                #pragma unroll
                for (int r = 0; r < 4; ++r) {
                    #pragma unroll
                    for (int d = 0; d < 3; ++d)
                        qacc[r][d] += edw[(qd*4 + r) * 53 + 36 + 3*v + d] * tt[r];
                }
            }
        }

        // ---- butterfly-reduce P,Q over the 4 sub-columns ----
        #pragma unroll
        for (int r = 0; r < 4; ++r) {
            float p = pacc[r];
            p += __shfl_xor(p, 4);
            p += __shfl_xor(p, 8);
            pacc[r] = p;
            #pragma unroll
            for (int d = 0; d < 3; ++d) {
                float q = qacc[r][d];
                q += __shfl_xor(q, 4);
                q += __shfl_xor(q, 8);
                qacc[r][d] = q;
            }
        }

        // ---- assemble 16x28 tile in LDS (reuse hbuf region) ----
        float* stf = reinterpret_cast<float*>(hb);
        #pragma unroll
        for (int r = 0; r < 4; ++r)
            stf[(qd*4 + r) * CH + cl] = outs[r];
        if (cl < 12) {
            int o = cl & 3, d = cl >> 2;
            #pragma unroll
            for (int r = 0; r < 4; ++r) {
                int m = qd * 4 + r;
                float qv = (d == 0) ? qacc[r][0] : ((d == 1) ? qacc[r][1] : qacc[r][2]);
                stf[m * CH + 16 + o * 3 + d] = edw[m * 53 + 48 + d] * pacc[r] + qv;
            }
        }
        WAVE_FENCE();   // stf written by all lanes, scatter reads cross-lane

        // ---- segmented scatter: runs of equal src -> int32 fixed-point atomics ----
        if (lane < CH) {
            int cur = srcb[wid][0];
            float acc2 = 0.0f;
            for (int m = 0; m < 16; ++m) {
                int s = srcb[wid][m];
                if (s != cur) {
                    atomicAdd(&outq[(size_t)cur * CH + lane], (int)rintf(acc2 * FIXS));
                    acc2 = 0.0f; cur = s;
                }
                acc2 += stf[m * CH + lane];
            }
            atomicAdd(&outq[(size_t)cur * CH + lane], (int)rintf(acc2 * FIXS));
        }
        WAVE_FENCE();   // next iteration's edata/h writes must not pass scatter reads

        // ---- rotate pipeline ----
        C = N;
        N.es = esF;
    }
}

// finalize: all accesses to d_out through int* (no int/float TBAA hazard)
__global__ __launch_bounds__(256) void finalize_kernel(int* __restrict__ outq,
                                                       const int* __restrict__ counts,
                                                       const float* __restrict__ node_attr) {
    int idx = blockIdx.x * 256 + threadIdx.x;
    if (idx < NODES * CH) {
        int n = idx / CH;
        int q = outq[idx];
        float r = ((float)q * FIXR) / fmaxf((float)counts[n], 1.0f) + node_attr[idx];
        outq[idx] = __float_as_int(r);
    }
}

extern "C" void kernel_launch(void* const* d_in, const int* in_sizes, int n_in,
                              void* d_out, int out_size, void* d_ws, size_t ws_size,
                              hipStream_t stream) {
    const float* node_attr = (const float*)d_in[0];
    const float* edge_attr = (const float*)d_in[1];
    const float* edge_sh   = (const float*)d_in[2];
    const int*   eidx      = (const int*)d_in[3];
    const float* W1 = (const float*)d_in[4];
    const float* b1 = (const float*)d_in[5];
    const float* W2 = (const float*)d_in[6];
    const float* b2 = (const float*)d_in[7];

    // ws layout (bytes): counts@0, offsets@204800, cursor@409600, bsum@614400, perm@616448
    const size_t OFF_OFFSETS = 204800;
    const size_t OFF_CURSOR  = 409600;
    const size_t OFF_BSUM    = 614400;
    const size_t OFF_PERM    = 616448;

    int* counts  = (int*)d_ws;
    int* offsets = (int*)((char*)d_ws + OFF_OFFSETS);
    int* cursor  = (int*)((char*)d_ws + OFF_CURSOR);
    int* bsum    = (int*)((char*)d_ws + OFF_BSUM);
    int* perm    = (int*)((char*)d_ws + OFF_PERM);

    const int EB = (EDGES + 255) / 256;  // 3125

    hipMemsetAsync(counts, 0, NODES * sizeof(int), stream);
    hipMemsetAsync(cursor, 0, NODES * sizeof(int), stream);
    hipMemsetAsync(d_out, 0, (size_t)NODES * CH * sizeof(float), stream);

    hist_kernel<<<EB, 256, 0, stream>>>(eidx, counts);
    scan1_kernel<<<SCAN_NB, 256, 0, stream>>>(counts, offsets, bsum);
    scan2_kernel<<<1, 256, 0, stream>>>(bsum);
    scan3_kernel<<<SCAN_NB, 256, 0, stream>>>(offsets, bsum);
    perm_kernel<<<EB, 256, 0, stream>>>(eidx, offsets, cursor, perm);

    tpconv_kernel<<<512, 256, 0, stream>>>(node_attr, edge_attr, edge_sh, eidx,
                                           W1, b1, W2, b2, (int*)d_out, perm);
    finalize_kernel<<<(NODES * CH + 255) / 256, 256, 0, stream>>>((int*)d_out, counts, node_attr);
}